// Round 5
// baseline (188.313 us; speedup 1.0000x reference)
//
#include <hip/hip_runtime.h>

namespace {
constexpr int S = 1024, I = 512, C = 8, H = 8;
constexpr float LNEPS = 1e-5f;
constexpr float SCALE = 0.35355339059327373f; // 8^-0.5
constexpr int CH = 512;                       // s-chunks; 2 rows/thread in kA1/kB1
}

// ---- packed float2 helpers (target v_pk_fma_f32 / v_pk_mul_f32) ----
__device__ __forceinline__ float2 pfma(float2 a, float s, float2 c) {
    return make_float2(fmaf(a.x, s, c.x), fmaf(a.y, s, c.y));
}
__device__ __forceinline__ float2 pmul(float2 a, float2 b) {
    return make_float2(a.x * b.x, a.y * b.y);
}
__device__ __forceinline__ float2 pmuls(float2 a, float s) {
    return make_float2(a.x * s, a.y * s);
}

// packed LayerNorm of a row pair: x2[c].x = row0, x2[c].y = row1
__device__ __forceinline__ void ln8x2(const float4 a0, const float4 b0,
                                      const float4 a1, const float4 b1,
                                      const float gm[8], const float bt[8],
                                      float2 x2[8]) {
    x2[0] = make_float2(a0.x, a1.x); x2[1] = make_float2(a0.y, a1.y);
    x2[2] = make_float2(a0.z, a1.z); x2[3] = make_float2(a0.w, a1.w);
    x2[4] = make_float2(b0.x, b1.x); x2[5] = make_float2(b0.y, b1.y);
    x2[6] = make_float2(b0.z, b1.z); x2[7] = make_float2(b0.w, b1.w);
    float2 mu = make_float2(0.f, 0.f);
#pragma unroll
    for (int c = 0; c < 8; c++) { mu.x += x2[c].x; mu.y += x2[c].y; }
    mu = pmuls(mu, 0.125f);
    float2 var = make_float2(0.f, 0.f);
#pragma unroll
    for (int c = 0; c < 8; c++) {
        float dx = x2[c].x - mu.x, dy = x2[c].y - mu.y;
        var.x += dx * dx; var.y += dy * dy;
    }
    float2 inv = make_float2(rsqrtf(var.x * 0.125f + LNEPS),
                             rsqrtf(var.y * 0.125f + LNEPS));
#pragma unroll
    for (int c = 0; c < 8; c++) {
        x2[c] = make_float2((x2[c].x - mu.x) * inv.x * gm[c] + bt[c],
                            (x2[c].y - mu.y) * inv.y * gm[c] + bt[c]);
    }
}

// kA1: part1[sc][i][c] = LN(m[2sc,i,:]) + LN(m[2sc+1,i,:])
__global__ __launch_bounds__(256, 4) void kA1_part(const float* __restrict__ m,
                                                   const float* __restrict__ gamma,
                                                   const float* __restrict__ beta,
                                                   float* __restrict__ part1) {
    int g = blockIdx.x * 256 + threadIdx.x;   // I*CH threads
    int i = g & (I - 1);
    int sc = g >> 9;
    float gm[8], bt[8];
#pragma unroll
    for (int c = 0; c < 8; c++) { gm[c] = gamma[c]; bt[c] = beta[c]; }
    const float4* m4 = (const float4*)m;
    int r0 = (sc * 2) * I + i, r1 = (sc * 2 + 1) * I + i;
    float2 x2[8];
    ln8x2(m4[r0 * 2], m4[r0 * 2 + 1], m4[r1 * 2], m4[r1 * 2 + 1], gm, bt, x2);
    float4* p4 = (float4*)&part1[((size_t)sc * I + i) * 8];
    p4[0] = make_float4(x2[0].x + x2[0].y, x2[1].x + x2[1].y,
                        x2[2].x + x2[2].y, x2[3].x + x2[3].y);
    p4[1] = make_float4(x2[4].x + x2[4].y, x2[5].x + x2[5].y,
                        x2[6].x + x2[6].y, x2[7].x + x2[7].y);
}

// kA2: reduce part1 over sc (8 i's/block), then
// qk[i,h,c2] = SCALE/S * sum_c (xbar[i].Wq_row(h,c)) * Wk[c,c2]
__global__ __launch_bounds__(256) void kA2_qk(const float* __restrict__ part1,
                                              const float* __restrict__ Wq,
                                              const float* __restrict__ Wk,
                                              float* __restrict__ qk) {
    __shared__ float red[4][64];
    __shared__ float xb[64];     // [il][c]
    __shared__ float sWq[512];
    __shared__ float sWk[64];
    int t = threadIdx.x;
    int i0 = blockIdx.x * 8;
    int w = t >> 6, l = t & 63;

    sWq[t] = Wq[t];
    sWq[t + 256] = Wq[t + 256];
    if (t < 64) sWk[t] = Wk[t];

    float sum = 0.f;
    for (int sc = w; sc < CH; sc += 4)
        sum += part1[((size_t)sc * I + i0) * 8 + l];
    red[w][l] = sum;
    __syncthreads();
    if (t < 64) xb[t] = red[0][t] + red[1][t] + red[2][t] + red[3][t];
    __syncthreads();

#pragma unroll
    for (int o = t; o < 512; o += 256) {
        int il = o >> 6, hc2 = o & 63, h = hc2 >> 3, c2 = hc2 & 7;
        float acc = 0.f;
#pragma unroll
        for (int c = 0; c < 8; c++) {
            float q = 0.f;
#pragma unroll
            for (int c3 = 0; c3 < 8; c3++)
                q += xb[il * 8 + c3] * sWq[(h * 8 + c) * 8 + c3];
            acc += q * sWk[c * 8 + c2];
        }
        qk[(i0 + il) * 64 + hc2] = acc * (SCALE / (float)S);
    }
}

// kB1: part2[sc][i][h] = sum over row pair of exp(qk[i,h,:].x)
__global__ __launch_bounds__(256, 4) void kB1_part(const float* __restrict__ m,
                                                   const float* __restrict__ gamma,
                                                   const float* __restrict__ beta,
                                                   const float* __restrict__ qk,
                                                   float* __restrict__ part2) {
    int g = blockIdx.x * 256 + threadIdx.x;   // I*CH threads
    int i = g & (I - 1);
    int sc = g >> 9;
    float gm[8], bt[8];
#pragma unroll
    for (int c = 0; c < 8; c++) { gm[c] = gamma[c]; bt[c] = beta[c]; }
    const float4* m4 = (const float4*)m;
    int r0 = (sc * 2) * I + i, r1 = (sc * 2 + 1) * I + i;
    float2 x2[8];
    ln8x2(m4[r0 * 2], m4[r0 * 2 + 1], m4[r1 * 2], m4[r1 * 2 + 1], gm, bt, x2);

    const float4* qk4 = (const float4*)qk;
    float acc[8];
#pragma unroll 1
    for (int h = 0; h < 8; h++) {
        float4 q0 = qk4[i * 16 + h * 2], q1 = qk4[i * 16 + h * 2 + 1];
        float2 l2 = make_float2(0.f, 0.f);
        l2 = pfma(x2[0], q0.x, l2); l2 = pfma(x2[1], q0.y, l2);
        l2 = pfma(x2[2], q0.z, l2); l2 = pfma(x2[3], q0.w, l2);
        l2 = pfma(x2[4], q1.x, l2); l2 = pfma(x2[5], q1.y, l2);
        l2 = pfma(x2[6], q1.z, l2); l2 = pfma(x2[7], q1.w, l2);
        acc[h] = __expf(l2.x) + __expf(l2.y);
    }
    float4* p4 = (float4*)&part2[((size_t)sc * I + i) * 8];
    p4[0] = make_float4(acc[0], acc[1], acc[2], acc[3]);
    p4[1] = make_float4(acc[4], acc[5], acc[6], acc[7]);
}

// kB2: reduce part2 over sc -> rden[i,h] = 1/denom, 8 i's per block
__global__ __launch_bounds__(256) void kB2_rden(const float* __restrict__ part2,
                                                float* __restrict__ rden) {
    __shared__ float red[4][64];
    int t = threadIdx.x;
    int i0 = blockIdx.x * 8;
    int w = t >> 6, l = t & 63;
    float sum = 0.f;
    for (int sc = w; sc < CH; sc += 4)
        sum += part2[((size_t)sc * I + i0) * 8 + l];
    red[w][l] = sum;
    __syncthreads();
    if (t < 64)
        rden[i0 * 8 + t] = 1.0f / (red[0][t] + red[1][t] + red[2][t] + red[3][t]);
}

// kC: final output. 4 rows/thread as 2 packed pairs; weights LDS-resident.
__global__ __launch_bounds__(256, 2) void kC_out(const float* __restrict__ m,
                                                 const float* __restrict__ gamma,
                                                 const float* __restrict__ beta,
                                                 const float* __restrict__ Wv,
                                                 const float* __restrict__ Wg,
                                                 const float* __restrict__ Wo,
                                                 const float* __restrict__ bo,
                                                 const float* __restrict__ qk,
                                                 const float* __restrict__ rden,
                                                 float* __restrict__ out) {
    __shared__ __align__(16) float sWv[64];
    __shared__ __align__(16) float sWg[512];
    __shared__ __align__(16) float sWoT[512];  // sWoT[j][c2] = Wo[c2][j]
    int t = threadIdx.x;
    if (t < 64) sWv[t] = Wv[t];
    sWg[t] = Wg[t];
    sWg[t + 256] = Wg[t + 256];
    {
        int j = t & 63, c2 = t >> 6;
        sWoT[j * 8 + c2] = Wo[c2 * 64 + j];
        sWoT[j * 8 + c2 + 4] = Wo[(c2 + 4) * 64 + j];
    }
    __syncthreads();

    float gm[8], bt[8];
#pragma unroll
    for (int c = 0; c < 8; c++) { gm[c] = gamma[c]; bt[c] = beta[c]; }

    int g = blockIdx.x * 256 + t;   // I*(S/4) threads
    int i = g & (I - 1);
    int sg = g >> 9;                // [0,256)
    const float4* m4 = (const float4*)m;

    // rows: pair0 = (sg, sg+256), pair1 = (sg+512, sg+768)
    int row[4];
#pragma unroll
    for (int r = 0; r < 4; r++) row[r] = (sg + 256 * r) * I + i;

    float2 x2[2][8];
    ln8x2(m4[row[0] * 2], m4[row[0] * 2 + 1], m4[row[1] * 2], m4[row[1] * 2 + 1],
          gm, bt, x2[0]);
    ln8x2(m4[row[2] * 2], m4[row[2] * 2 + 1], m4[row[3] * 2], m4[row[3] * 2 + 1],
          gm, bt, x2[1]);

    const float4* sWv4 = (const float4*)sWv;
    const float4* sWg4 = (const float4*)sWg;
    const float4* sWoT4 = (const float4*)sWoT;

    float2 v2[2][8];
#pragma unroll
    for (int c = 0; c < 8; c++) {
        float4 w0 = sWv4[c * 2], w1 = sWv4[c * 2 + 1];
#pragma unroll
        for (int p = 0; p < 2; p++) {
            float2 acc = make_float2(0.f, 0.f);
            acc = pfma(x2[p][0], w0.x, acc); acc = pfma(x2[p][1], w0.y, acc);
            acc = pfma(x2[p][2], w0.z, acc); acc = pfma(x2[p][3], w0.w, acc);
            acc = pfma(x2[p][4], w1.x, acc); acc = pfma(x2[p][5], w1.y, acc);
            acc = pfma(x2[p][6], w1.z, acc); acc = pfma(x2[p][7], w1.w, acc);
            v2[p][c] = acc;
        }
    }

    float bov[8];
#pragma unroll
    for (int c = 0; c < 8; c++) bov[c] = bo[c];
    float2 oacc[2][8];
#pragma unroll
    for (int p = 0; p < 2; p++)
#pragma unroll
        for (int c2 = 0; c2 < 8; c2++) oacc[p][c2] = make_float2(bov[c2], bov[c2]);

    const float4* qk4 = (const float4*)qk;
#pragma unroll 1
    for (int h = 0; h < 8; h++) {
        float4 q0 = qk4[i * 16 + h * 2], q1 = qk4[i * 16 + h * 2 + 1];
        float rd = rden[i * 8 + h];
        float2 a2[2];
#pragma unroll
        for (int p = 0; p < 2; p++) {
            float2 l2 = make_float2(0.f, 0.f);
            l2 = pfma(x2[p][0], q0.x, l2); l2 = pfma(x2[p][1], q0.y, l2);
            l2 = pfma(x2[p][2], q0.z, l2); l2 = pfma(x2[p][3], q0.w, l2);
            l2 = pfma(x2[p][4], q1.x, l2); l2 = pfma(x2[p][5], q1.y, l2);
            l2 = pfma(x2[p][6], q1.z, l2); l2 = pfma(x2[p][7], q1.w, l2);
            a2[p] = pmuls(make_float2(__expf(l2.x), __expf(l2.y)), rd);
        }
#pragma unroll
        for (int c = 0; c < 8; c++) {
            int hc = h * 8 + c;
            float4 wg0 = sWg4[hc * 2], wg1 = sWg4[hc * 2 + 1];
            float2 o2[2];
#pragma unroll
            for (int p = 0; p < 2; p++) {
                float2 z2 = make_float2(0.f, 0.f);
                z2 = pfma(x2[p][0], wg0.x, z2); z2 = pfma(x2[p][1], wg0.y, z2);
                z2 = pfma(x2[p][2], wg0.z, z2); z2 = pfma(x2[p][3], wg0.w, z2);
                z2 = pfma(x2[p][4], wg1.x, z2); z2 = pfma(x2[p][5], wg1.y, z2);
                z2 = pfma(x2[p][6], wg1.z, z2); z2 = pfma(x2[p][7], wg1.w, z2);
                float2 g2 = make_float2(
                    __builtin_amdgcn_rcpf(1.0f + __expf(-z2.x)),
                    __builtin_amdgcn_rcpf(1.0f + __expf(-z2.y)));
                o2[p] = pmul(pmul(g2, a2[p]), v2[p][c]);
            }
            float4 wo0 = sWoT4[hc * 2], wo1 = sWoT4[hc * 2 + 1];
#pragma unroll
            for (int p = 0; p < 2; p++) {
                oacc[p][0] = pfma(o2[p], wo0.x, oacc[p][0]);
                oacc[p][1] = pfma(o2[p], wo0.y, oacc[p][1]);
                oacc[p][2] = pfma(o2[p], wo0.z, oacc[p][2]);
                oacc[p][3] = pfma(o2[p], wo0.w, oacc[p][3]);
                oacc[p][4] = pfma(o2[p], wo1.x, oacc[p][4]);
                oacc[p][5] = pfma(o2[p], wo1.y, oacc[p][5]);
                oacc[p][6] = pfma(o2[p], wo1.z, oacc[p][6]);
                oacc[p][7] = pfma(o2[p], wo1.w, oacc[p][7]);
            }
        }
    }

    float4* out4 = (float4*)out;
#pragma unroll
    for (int p = 0; p < 2; p++) {
        out4[row[p * 2] * 2] =
            make_float4(oacc[p][0].x, oacc[p][1].x, oacc[p][2].x, oacc[p][3].x);
        out4[row[p * 2] * 2 + 1] =
            make_float4(oacc[p][4].x, oacc[p][5].x, oacc[p][6].x, oacc[p][7].x);
        out4[row[p * 2 + 1] * 2] =
            make_float4(oacc[p][0].y, oacc[p][1].y, oacc[p][2].y, oacc[p][3].y);
        out4[row[p * 2 + 1] * 2 + 1] =
            make_float4(oacc[p][4].y, oacc[p][5].y, oacc[p][6].y, oacc[p][7].y);
    }
}

extern "C" void kernel_launch(void* const* d_in, const int* in_sizes, int n_in,
                              void* d_out, int out_size, void* d_ws, size_t ws_size,
                              hipStream_t stream) {
    const float* m     = (const float*)d_in[0];
    const float* gamma = (const float*)d_in[1];
    const float* beta  = (const float*)d_in[2];
    const float* Wq    = (const float*)d_in[3];
    const float* Wk    = (const float*)d_in[4];
    const float* Wv    = (const float*)d_in[5];
    const float* Wg    = (const float*)d_in[6];
    const float* Wo    = (const float*)d_in[7];
    const float* bo    = (const float*)d_in[8];
    float* out = (float*)d_out;

    float* ws    = (float*)d_ws;
    float* part1 = ws;                              // CH*I*8 = 2M floats (8MB)
    float* part2 = part1 + (size_t)CH * I * C;      // 8MB
    float* qk    = part2 + (size_t)CH * I * C;      // I*64
    float* rden  = qk + (size_t)I * 64;             // I*8

    kA1_part<<<I * CH / 256, 256, 0, stream>>>(m, gamma, beta, part1);
    kA2_qk<<<I / 8, 256, 0, stream>>>(part1, Wq, Wk, qk);
    kB1_part<<<I * CH / 256, 256, 0, stream>>>(m, gamma, beta, qk, part2);
    kB2_rden<<<I / 8, 256, 0, stream>>>(part2, rden);
    kC_out<<<I * (S / 4) / 256, 256, 0, stream>>>(m, gamma, beta, Wv, Wg, Wo, bo,
                                                  qk, rden, out);
}